// Round 5
// baseline (62.761 us; speedup 1.0000x reference)
//
#include <hip/hip_runtime.h>
#include <hip/hip_bf16.h>

#define B_SENT 128
#define L_TOK  256
#define D_DIM  1024
#define TM     64              // tokens per block (4 tiles per sentence)
#define BK     32              // K per step == MFMA K
#define NKB    (D_DIM / BK)    // 32 K-steps

typedef __attribute__((ext_vector_type(8))) short bf16x8;
typedef __attribute__((ext_vector_type(4))) float f32x4;

__device__ __forceinline__ unsigned short f2bf(float f) {
    return __builtin_bit_cast(unsigned short, __float2bfloat16(f));
}
__device__ __forceinline__ float softplus_f(float x) {
    float ax = fabsf(x);
    return fmaxf(x, 0.0f) + __logf(1.0f + __expf(-ax));
}
__device__ __forceinline__ bf16x8 cvt8f(const float4& lo, const float4& hi) {
    bf16x8 u;
    u[0] = (short)f2bf(lo.x); u[1] = (short)f2bf(lo.y);
    u[2] = (short)f2bf(lo.z); u[3] = (short)f2bf(lo.w);
    u[4] = (short)f2bf(hi.x); u[5] = (short)f2bf(hi.y);
    u[6] = (short)f2bf(hi.z); u[7] = (short)f2bf(hi.w);
    return u;
}

// async global->LDS, 16 B per lane. LDS base must be wave-uniform.
__device__ __forceinline__ void gl_lds16(const void* g, void* l) {
    __builtin_amdgcn_global_load_lds(
        (const __attribute__((address_space(1))) unsigned int*)g,
        (__attribute__((address_space(3))) unsigned int*)l, 16, 0, 0);
}

// ---------------------------------------------------------------------------
// Pre-pack glob (f32) -> bf16 MFMA B-fragments, BK=32 chunks (512 KB total):
// packed[((side*32 + kb)*512 + n*64 + lane)*8 + e]
//   = glob[side][n*16 + (lane&15)][kb*32 + (lane>>4)*8 + e]
// ---------------------------------------------------------------------------
__global__ __launch_bounds__(256) void pack_g_kernel(
    const float* __restrict__ g0, const float* __restrict__ g1,
    short* __restrict__ packed)
{
    const int idx  = blockIdx.x * 256 + threadIdx.x;   // 0..32767
    const int lane = idx & 63;
    const int n    = (idx >> 6) & 7;
    const int kb   = (idx >> 9) & 31;
    const int side = idx >> 14;
    const int row  = n * 16 + (lane & 15);
    const int col  = kb * 32 + (lane >> 4) * 8;
    const float* g = side ? g1 : g0;
    const float4 v0 = *reinterpret_cast<const float4*>(&g[(size_t)row * D_DIM + col]);
    const float4 v1 = *reinterpret_cast<const float4*>(&g[(size_t)row * D_DIM + col + 4]);
    *reinterpret_cast<bf16x8*>(&packed[(size_t)idx * 8]) = cvt8f(v0, v1);
}

// ---------------------------------------------------------------------------
// Main: m97-style 2-barrier dbuf loop, ALL staging via global_load_lds.
// Block = 64 tokens x 128 sentences, 4 waves (wave = 16 token rows).
// LDS fragment-major: A region (w*2+h): lane l -> tok row w*16+(l&15),
// cols kb*32 + (l>>4)*8 + h*4 (4 f32). B region n: lane l -> frag bytes.
// ---------------------------------------------------------------------------
__global__ __launch_bounds__(256, 4) void mi_main_kernel(
    const float* __restrict__ tok0, const float* __restrict__ tok1,
    const int* __restrict__ len0, const int* __restrict__ len1,
    const short* __restrict__ packed, float* __restrict__ acc_ws)
{
    const int side = blockIdx.y;
    const float* tok = side ? tok1 : tok0;
    const int*   len = side ? len1 : len0;

    const int tile   = blockIdx.x;       // 0..511
    const int tb     = tile * TM;
    const int b_sent = tile >> 2;        // 4 tiles per sentence
    const int count  = max(1, len[b_sent]) - (tile & 3) * TM;
    if (count <= 0) return;              // fully-masked tile: contributes 0

    const int tid  = threadIdx.x;
    const int wave = tid >> 6;
    const int lane = tid & 63;
    const int lrow = lane & 15;
    const int kgrp = lane >> 4;

    __shared__ float As[2][2048];        // 2 x 8 KB (8 regions x 64 lanes x 16 B)
    __shared__ short Bs[2][4096];        // 2 x 8 KB (8 frags   x 64 lanes x 16 B)
    __shared__ float sred[8];

    // per-thread global sources (constant across kb, + kb*BK / + kb*4096)
    const float* asrc = tok + (size_t)(tb + wave * 16 + lrow) * D_DIM + kgrp * 8;
    const short* bchunk = packed + (size_t)side * NKB * 4096;
    const int br0 = ((wave * 2 + 0) * 64 + lane) * 8;   // short offsets in chunk
    const int br1 = ((wave * 2 + 1) * 64 + lane) * 8;

    f32x4 acc[8];
#pragma unroll
    for (int n = 0; n < 8; ++n) acc[n] = (f32x4){0.f, 0.f, 0.f, 0.f};

    auto stage = [&](int buf, int kb) {
        const float* a = asrc + kb * BK;
        gl_lds16(a,     &As[buf][(wave * 2 + 0) * 256]);
        gl_lds16(a + 4, &As[buf][(wave * 2 + 1) * 256]);
        const short* bc = bchunk + (size_t)kb * 4096;
        gl_lds16(bc + br0, &Bs[buf][(wave * 2 + 0) * 512]);
        gl_lds16(bc + br1, &Bs[buf][(wave * 2 + 1) * 512]);
    };

    auto compute = [&](int buf) {
        const f32x4 alo = *reinterpret_cast<const f32x4*>(
            &As[buf][(wave * 2 + 0) * 256 + lane * 4]);
        const f32x4 ahi = *reinterpret_cast<const f32x4*>(
            &As[buf][(wave * 2 + 1) * 256 + lane * 4]);
        bf16x8 af;
        af[0] = (short)f2bf(alo[0]); af[1] = (short)f2bf(alo[1]);
        af[2] = (short)f2bf(alo[2]); af[3] = (short)f2bf(alo[3]);
        af[4] = (short)f2bf(ahi[0]); af[5] = (short)f2bf(ahi[1]);
        af[6] = (short)f2bf(ahi[2]); af[7] = (short)f2bf(ahi[3]);
#pragma unroll
        for (int n = 0; n < 8; ++n) {
            bf16x8 b = *reinterpret_cast<const bf16x8*>(&Bs[buf][(n * 64 + lane) * 8]);
            acc[n] = __builtin_amdgcn_mfma_f32_16x16x32_bf16(af, b, acc[n], 0, 0, 0);
        }
    };

    stage(0, 0);
    __syncthreads();                     // vmcnt(0) drain lands here
#pragma unroll 1
    for (int kb = 0; kb < NKB; ++kb) {
        const int cur = kb & 1;
        if (kb + 1 < NKB) stage(cur ^ 1, kb + 1);   // async, flies under compute
        compute(cur);
        __syncthreads();                 // rendezvous + drain of staged loads
    }

    // ---- epilogue: masked softplus reduction ----
    // C/D layout: col = lane&15 (sentence), row = kgrp*4 + j (token in frag)
    float ep = 0.f, en = 0.f;
#pragma unroll
    for (int n = 0; n < 8; ++n) {
        const int g = n * 16 + lrow;
#pragma unroll
        for (int j = 0; j < 4; ++j) {
            const int rl = wave * 16 + kgrp * 4 + j;   // local token row
            if (rl < count) {
                float res = acc[n][j];
                float sp  = softplus_f(res);
                if (g == b_sent) ep += res - sp;   // -softplus(-res)
                else             en += sp;         // softplus(-res)+res
            }
        }
    }

#pragma unroll
    for (int off = 32; off; off >>= 1) {
        ep += __shfl_down(ep, off);
        en += __shfl_down(en, off);
    }
    if (lane == 0) { sred[wave * 2] = ep; sred[wave * 2 + 1] = en; }
    __syncthreads();
    if (tid == 0) {
        float tep = sred[0] + sred[2] + sred[4] + sred[6];
        float ten = sred[1] + sred[3] + sred[5] + sred[7];
        atomicAdd(&acc_ws[side * 2 + 0], tep);
        atomicAdd(&acc_ws[side * 2 + 1], ten);
    }
}

__global__ void mi_finalize_kernel(const int* __restrict__ len0,
                                   const int* __restrict__ len1,
                                   const float* __restrict__ acc_ws,
                                   float* __restrict__ out)
{
    const int lane = threadIdx.x;   // 1 wave
    int s0 = 0, s1 = 0;
    for (int i = lane; i < B_SENT; i += 64) {
        s0 += max(1, len0[i]);
        s1 += max(1, len1[i]);
    }
#pragma unroll
    for (int off = 32; off; off >>= 1) {
        s0 += __shfl_down(s0, off);
        s1 += __shfl_down(s1, off);
    }
    if (lane == 0) {
        const float num_nodes = (float)(s0 + s1);
        const float ep = acc_ws[0] + acc_ws[2];
        const float en = acc_ws[1] + acc_ws[3];
        out[0] = en / (num_nodes * (float)(B_SENT - 1)) - ep / num_nodes;
        out[1] = ((float)s0 + (float)s1) / (2.0f * (float)B_SENT);
    }
}

extern "C" void kernel_launch(void* const* d_in, const int* in_sizes, int n_in,
                              void* d_out, int out_size, void* d_ws, size_t ws_size,
                              hipStream_t stream) {
    const float* tok0  = (const float*)d_in[0];
    const float* tok1  = (const float*)d_in[1];
    const float* glob0 = (const float*)d_in[2];
    const float* glob1 = (const float*)d_in[3];
    const int*   len0  = (const int*)d_in[4];
    const int*   len1  = (const int*)d_in[5];
    float* out = (float*)d_out;

    float* acc    = (float*)d_ws;                       // 4 floats @ offset 0
    short* packed = (short*)((char*)d_ws + 256);        // 512 KB bf16 fragments

    hipMemsetAsync(d_ws, 0, 256, stream);
    pack_g_kernel<<<128, 256, 0, stream>>>(glob0, glob1, packed);

    dim3 grid(32768 / TM, 2);   // 512 token-tiles x 2 sides
    mi_main_kernel<<<grid, 256, 0, stream>>>(tok0, tok1, len0, len1, packed, acc);
    mi_finalize_kernel<<<1, 64, 0, stream>>>(len0, len1, acc, out);
}

// Round 6
// 56.277 us; speedup vs baseline: 1.1152x; 1.1152x over previous
//
#include <hip/hip_runtime.h>
#include <hip/hip_bf16.h>

#define B_SENT 128
#define L_TOK  256
#define D_DIM  1024
#define TM     128             // tokens per block (2 tiles per sentence)
#define BK     32              // K per step == MFMA K
#define NKB    (D_DIM / BK)    // 32 K-steps

typedef __attribute__((ext_vector_type(8))) short bf16x8;
typedef __attribute__((ext_vector_type(4))) float f32x4;

#define WAITVM(N) asm volatile("s_waitcnt vmcnt(" #N ")" ::: "memory")

__device__ __forceinline__ unsigned short f2bf(float f) {
    return __builtin_bit_cast(unsigned short, __float2bfloat16(f));
}
__device__ __forceinline__ float softplus_f(float x) {
    float ax = fabsf(x);
    return fmaxf(x, 0.0f) + __logf(1.0f + __expf(-ax));
}
__device__ __forceinline__ bf16x8 cvt8f(const float4& lo, const float4& hi) {
    bf16x8 u;
    u[0] = (short)f2bf(lo.x); u[1] = (short)f2bf(lo.y);
    u[2] = (short)f2bf(lo.z); u[3] = (short)f2bf(lo.w);
    u[4] = (short)f2bf(hi.x); u[5] = (short)f2bf(hi.y);
    u[6] = (short)f2bf(hi.z); u[7] = (short)f2bf(hi.w);
    return u;
}

// async global->LDS, 16 B per lane. LDS base wave-uniform; global src per-lane.
__device__ __forceinline__ void gl_lds16(const void* g, void* l) {
    __builtin_amdgcn_global_load_lds(
        (const __attribute__((address_space(1))) unsigned int*)g,
        (__attribute__((address_space(3))) unsigned int*)l, 16, 0, 0);
}

// ---------------------------------------------------------------------------
// Pre-pack glob (f32) -> bf16 MFMA B-fragments, BK=32 chunks (512 KB total):
// packed[[side][kb][n][lane][e]] = glob[side][n*16+(lane&15)][kb*32+(lane>>4)*8+e]
// ---------------------------------------------------------------------------
__global__ __launch_bounds__(256) void pack_g_kernel(
    const float* __restrict__ g0, const float* __restrict__ g1,
    short* __restrict__ packed)
{
    const int idx  = blockIdx.x * 256 + threadIdx.x;   // 0..32767
    const int lane = idx & 63;
    const int n    = (idx >> 6) & 7;
    const int kb   = (idx >> 9) & 31;
    const int side = idx >> 14;
    const int row  = n * 16 + (lane & 15);
    const int col  = kb * 32 + (lane >> 4) * 8;
    const float* g = side ? g1 : g0;
    const float4 v0 = *reinterpret_cast<const float4*>(&g[(size_t)row * D_DIM + col]);
    const float4 v1 = *reinterpret_cast<const float4*>(&g[(size_t)row * D_DIM + col + 4]);
    *reinterpret_cast<bf16x8*>(&packed[(size_t)idx * 8]) = cvt8f(v0, v1);
}

// ---------------------------------------------------------------------------
// Main: counted-vmcnt pipelined GEMM (T3+T4). Block = 128 tokens x 128
// sentences, 8 waves (16 token rows each). 3 LDS buffers, 2 stages in
// flight, s_waitcnt vmcnt(3) + raw s_barrier per K-step (never drain to 0).
// ---------------------------------------------------------------------------
__global__ __launch_bounds__(512, 4) void mi_main_kernel(
    const float* __restrict__ tok0, const float* __restrict__ tok1,
    const int* __restrict__ len0, const int* __restrict__ len1,
    const short* __restrict__ packed, float* __restrict__ acc_ws)
{
    const int side = blockIdx.y;
    const float* tok = side ? tok1 : tok0;
    const int*   len = side ? len1 : len0;

    const int tile   = blockIdx.x;       // 0..255
    const int b_sent = tile >> 1;        // 2 tiles per sentence
    const int half   = tile & 1;
    const int tb     = b_sent * L_TOK + half * TM;
    const int count  = max(1, len[b_sent]) - half * TM;
    if (count <= 0) return;              // uniform whole-block exit

    const int tid  = threadIdx.x;
    const int wave = tid >> 6;           // 0..7
    const int lane = tid & 63;
    const int lrow = lane & 15;
    const int kgrp = lane >> 4;

    __shared__ float As[3][4096];        // 3 x 16 KB: 16 regions x 64 lanes x 16 B
    __shared__ short Bs[3][4096];        // 3 x  8 KB:  8 regions x 64 lanes x 16 B
    __shared__ float sred[16];

    // A source: row clamped to count-1 (masked rows fetch dup lines -> L2 hits;
    // garbage lands only in acc entries the epilogue skips).
    const int arow = min(wave * 16 + lrow, count - 1);
    const float* asrc = tok + (size_t)(tb + arow) * D_DIM + kgrp * 8;
    const short* bchunk = packed + (size_t)side * NKB * 4096;
    const int boff = (wave * 64 + lane) * 8;   // this wave's B-region source

    f32x4 acc[8];
#pragma unroll
    for (int n = 0; n < 8; ++n) acc[n] = (f32x4){0.f, 0.f, 0.f, 0.f};

    auto stage = [&](int buf, int kb) {            // exactly 3 gl_lds per wave
        const float* a = asrc + kb * BK;
        gl_lds16(a,     &As[buf][(wave * 2 + 0) * 256]);
        gl_lds16(a + 4, &As[buf][(wave * 2 + 1) * 256]);
        gl_lds16(bchunk + (size_t)kb * 4096 + boff, &Bs[buf][wave * 512]);
    };

    auto compute = [&](int buf) {
        const f32x4 alo = *reinterpret_cast<const f32x4*>(
            &As[buf][(wave * 2 + 0) * 256 + lane * 4]);
        const f32x4 ahi = *reinterpret_cast<const f32x4*>(
            &As[buf][(wave * 2 + 1) * 256 + lane * 4]);
        bf16x8 af;
        af[0] = (short)f2bf(alo[0]); af[1] = (short)f2bf(alo[1]);
        af[2] = (short)f2bf(alo[2]); af[3] = (short)f2bf(alo[3]);
        af[4] = (short)f2bf(ahi[0]); af[5] = (short)f2bf(ahi[1]);
        af[6] = (short)f2bf(ahi[2]); af[7] = (short)f2bf(ahi[3]);
#pragma unroll
        for (int n = 0; n < 8; ++n) {
            bf16x8 b = *reinterpret_cast<const bf16x8*>(&Bs[buf][(n * 64 + lane) * 8]);
            acc[n] = __builtin_amdgcn_mfma_f32_16x16x32_bf16(af, b, acc[n], 0, 0, 0);
        }
    };

    // ---- pipelined K-loop: 2 stages always in flight ----
    stage(0, 0);
    stage(1, 1);
#pragma unroll 1
    for (int kb = 0; kb < NKB - 1; ++kb) {
        WAITVM(3);                         // oldest stage (buf kb%3) landed
        __builtin_amdgcn_s_barrier();      // all waves' buf-kb loads visible
        asm volatile("" ::: "memory");
        if (kb + 2 < NKB) stage((kb + 2) % 3, kb + 2);
        compute(kb % 3);
    }
    WAITVM(0);                             // tail: drain last stage
    __builtin_amdgcn_s_barrier();
    asm volatile("" ::: "memory");
    compute((NKB - 1) % 3);

    // ---- epilogue: masked softplus reduction ----
    // C/D layout: col = lane&15 (sentence), row = kgrp*4 + j (token in frag)
    float ep = 0.f, en = 0.f;
#pragma unroll
    for (int n = 0; n < 8; ++n) {
        const int g = n * 16 + lrow;
#pragma unroll
        for (int j = 0; j < 4; ++j) {
            const int rl = wave * 16 + kgrp * 4 + j;   // local token row
            if (rl < count) {
                float res = acc[n][j];
                float sp  = softplus_f(res);
                if (g == b_sent) ep += res - sp;   // -softplus(-res)
                else             en += sp;         // softplus(-res)+res
            }
        }
    }

#pragma unroll
    for (int off = 32; off; off >>= 1) {
        ep += __shfl_down(ep, off);
        en += __shfl_down(en, off);
    }
    if (lane == 0) { sred[wave * 2] = ep; sred[wave * 2 + 1] = en; }
    __syncthreads();
    if (tid == 0) {
        float tep = 0.f, ten = 0.f;
#pragma unroll
        for (int w = 0; w < 8; ++w) { tep += sred[w * 2]; ten += sred[w * 2 + 1]; }
        atomicAdd(&acc_ws[side * 2 + 0], tep);
        atomicAdd(&acc_ws[side * 2 + 1], ten);
    }
}

__global__ void mi_finalize_kernel(const int* __restrict__ len0,
                                   const int* __restrict__ len1,
                                   const float* __restrict__ acc_ws,
                                   float* __restrict__ out)
{
    const int lane = threadIdx.x;   // 1 wave
    int s0 = 0, s1 = 0;
    for (int i = lane; i < B_SENT; i += 64) {
        s0 += max(1, len0[i]);
        s1 += max(1, len1[i]);
    }
#pragma unroll
    for (int off = 32; off; off >>= 1) {
        s0 += __shfl_down(s0, off);
        s1 += __shfl_down(s1, off);
    }
    if (lane == 0) {
        const float num_nodes = (float)(s0 + s1);
        const float ep = acc_ws[0] + acc_ws[2];
        const float en = acc_ws[1] + acc_ws[3];
        out[0] = en / (num_nodes * (float)(B_SENT - 1)) - ep / num_nodes;
        out[1] = ((float)s0 + (float)s1) / (2.0f * (float)B_SENT);
    }
}

extern "C" void kernel_launch(void* const* d_in, const int* in_sizes, int n_in,
                              void* d_out, int out_size, void* d_ws, size_t ws_size,
                              hipStream_t stream) {
    const float* tok0  = (const float*)d_in[0];
    const float* tok1  = (const float*)d_in[1];
    const float* glob0 = (const float*)d_in[2];
    const float* glob1 = (const float*)d_in[3];
    const int*   len0  = (const int*)d_in[4];
    const int*   len1  = (const int*)d_in[5];
    float* out = (float*)d_out;

    float* acc    = (float*)d_ws;                       // 4 floats @ offset 0
    short* packed = (short*)((char*)d_ws + 256);        // 512 KB bf16 fragments

    hipMemsetAsync(d_ws, 0, 256, stream);
    pack_g_kernel<<<128, 256, 0, stream>>>(glob0, glob1, packed);

    dim3 grid(32768 / TM, 2);   // 256 token-tiles x 2 sides
    mi_main_kernel<<<grid, 512, 0, stream>>>(tok0, tok1, len0, len1, packed, acc);
    mi_finalize_kernel<<<1, 64, 0, stream>>>(len0, len1, acc, out);
}